// Round 8
// baseline (296.160 us; speedup 1.0000x reference)
//
#include <hip/hip_runtime.h>

typedef __attribute__((ext_vector_type(8))) short short8;
typedef __attribute__((ext_vector_type(4))) float f32x4;
typedef __attribute__((ext_vector_type(16))) float f32x16;
typedef __attribute__((ext_vector_type(4))) unsigned short u16x4;
typedef __attribute__((ext_vector_type(4))) float float4v;

#define AS1 __attribute__((address_space(1)))
#define AS3 __attribute__((address_space(3)))

#define T_SEQ 2048
#define C_EMB 1024
#define NHEAD 16
#define NB    4
#define SCL_Q 0.18033688f   // 0.125 * log2(e)

__device__ __forceinline__ unsigned short f2bf(float f) {
    union { float f; unsigned u; } cv; cv.f = f;
    unsigned u = cv.u;
    unsigned r = (u + 0x7FFFu + ((u >> 16) & 1u)) >> 16;
    return (unsigned short)r;
}

__device__ __forceinline__ void async_load16(const void* g, void* l) {
    __builtin_amdgcn_global_load_lds((const AS1 unsigned*)g, (AS3 unsigned*)l, 16, 0, 0);
}

// ---------------- f32 -> bf16 convert ----------------
__global__ void cvt_bf16(const float* __restrict__ in, unsigned short* __restrict__ out, int n4) {
    int i = blockIdx.x * blockDim.x + threadIdx.x;
    if (i >= n4) return;
    float4v v = ((const float4v*)in)[i];
    u16x4 o;
    o[0] = f2bf(v[0]); o[1] = f2bf(v[1]); o[2] = f2bf(v[2]); o[3] = f2bf(v[3]);
    ((u16x4*)out)[i] = o;
}

// ---------------- fused QKV GEMM: [8192,1024] x [3072,1024]^T ----------------
__global__ void gemm_qkv(const unsigned short* __restrict__ A,
                         const unsigned short* __restrict__ W,
                         const float* __restrict__ bq,
                         const float* __restrict__ bk,
                         const float* __restrict__ bv,
                         unsigned short* __restrict__ Qo,
                         unsigned short* __restrict__ Ko,
                         unsigned short* __restrict__ Vt) {
    __shared__ __align__(16) unsigned short As[128 * 32];
    __shared__ __align__(16) unsigned short Bs[128 * 32];
    const int tid  = threadIdx.x;
    const int wid  = tid >> 6;
    const int lane = tid & 63;
    const int lg = lane >> 4, lr = lane & 15;
    const int wr = wid >> 1, wc = wid & 1;
    const int n0 = blockIdx.x * 128;
    const int m0 = blockIdx.y * 128;
    const int K = 1024;

    f32x4 acc[4][4] = {};

    for (int kt = 0; kt < K; kt += 32) {
        #pragma unroll
        for (int r = 0; r < 2; ++r) {
            int cb = r * 4 + wid;
            int chunk = cb * 64 + lane;
            int row = chunk >> 2;
            int col = (chunk & 3) * 8;
            async_load16(&A[(size_t)(m0 + row) * K + kt + col], (char*)As + cb * 1024);
            async_load16(&W[(size_t)(n0 + row) * K + kt + col], (char*)Bs + cb * 1024);
        }
        __syncthreads();
        short8 af[4], bfr[4];
        #pragma unroll
        for (int m = 0; m < 4; ++m)
            af[m] = *(const short8*)&As[(wr * 64 + m * 16 + lr) * 32 + lg * 8];
        #pragma unroll
        for (int n = 0; n < 4; ++n)
            bfr[n] = *(const short8*)&Bs[(wc * 64 + n * 16 + lr) * 32 + lg * 8];
        #pragma unroll
        for (int m = 0; m < 4; ++m)
            #pragma unroll
            for (int n = 0; n < 4; ++n)
                acc[m][n] = __builtin_amdgcn_mfma_f32_16x16x32_bf16(af[m], bfr[n], acc[m][n], 0, 0, 0);
        __syncthreads();
    }

    const int sel = n0 >> 10;                       // 0=Q 1=K 2=V (block-uniform)
    const int nl0 = n0 & 1023;
    const float* bias = (sel == 0) ? bq : (sel == 1) ? bk : bv;
    const float scale = (sel == 0) ? SCL_Q : 1.0f;

    #pragma unroll
    for (int n = 0; n < 4; ++n) {
        int cc = nl0 + wc * 64 + n * 16 + lr;
        float bvv = bias[cc];
        #pragma unroll
        for (int m = 0; m < 4; ++m) {
            int rr0 = m0 + wr * 64 + m * 16 + lg * 4;
            u16x4 pk;
            #pragma unroll
            for (int r = 0; r < 4; ++r)
                pk[r] = f2bf((acc[m][n][r] + bvv) * scale);
            if (sel == 2) {
                size_t idx = ((size_t)(rr0 >> 11) * 1024 + cc) * 2048 + (rr0 & 2047);
                *(u16x4*)&Vt[idx] = pk;
            } else {
                unsigned short* out = (sel == 0) ? Qo : Ko;
                #pragma unroll
                for (int r = 0; r < 4; ++r)
                    out[(size_t)(rr0 + r) * 1024 + cc] = pk[r];
            }
        }
    }
}

// ---------------- proj GEMM: C[M,N] = A[M,K]*B[N,K]^T + bias (f32 out) ----------------
__global__ void gemm_proj(const unsigned short* __restrict__ A,
                          const unsigned short* __restrict__ B,
                          const float* __restrict__ bias,
                          float* __restrict__ Cout,
                          int M, int N, int K) {
    __shared__ __align__(16) unsigned short As[128 * 32];
    __shared__ __align__(16) unsigned short Bs[128 * 32];
    const int tid  = threadIdx.x;
    const int wid  = tid >> 6;
    const int lane = tid & 63;
    const int lg = lane >> 4, lr = lane & 15;
    const int wr = wid >> 1, wc = wid & 1;
    const int n0 = blockIdx.x * 128;
    const int m0 = blockIdx.y * 128;

    f32x4 acc[4][4] = {};

    for (int kt = 0; kt < K; kt += 32) {
        #pragma unroll
        for (int r = 0; r < 2; ++r) {
            int cb = r * 4 + wid;
            int chunk = cb * 64 + lane;
            int row = chunk >> 2;
            int col = (chunk & 3) * 8;
            async_load16(&A[(size_t)(m0 + row) * K + kt + col], (char*)As + cb * 1024);
            async_load16(&B[(size_t)(n0 + row) * K + kt + col], (char*)Bs + cb * 1024);
        }
        __syncthreads();
        short8 af[4], bfr[4];
        #pragma unroll
        for (int m = 0; m < 4; ++m)
            af[m] = *(const short8*)&As[(wr * 64 + m * 16 + lr) * 32 + lg * 8];
        #pragma unroll
        for (int n = 0; n < 4; ++n)
            bfr[n] = *(const short8*)&Bs[(wc * 64 + n * 16 + lr) * 32 + lg * 8];
        #pragma unroll
        for (int m = 0; m < 4; ++m)
            #pragma unroll
            for (int n = 0; n < 4; ++n)
                acc[m][n] = __builtin_amdgcn_mfma_f32_16x16x32_bf16(af[m], bfr[n], acc[m][n], 0, 0, 0);
        __syncthreads();
    }

    #pragma unroll
    for (int n = 0; n < 4; ++n) {
        int cc = n0 + wc * 64 + n * 16 + lr;
        float bvv = bias[cc];
        #pragma unroll
        for (int m = 0; m < 4; ++m) {
            int rr0 = m0 + wr * 64 + m * 16 + lg * 4;
            #pragma unroll
            for (int r = 0; r < 4; ++r)
                Cout[(size_t)(rr0 + r) * N + cc] = acc[m][n][r] + bvv;
        }
    }
}

// ---------------- flash attention (causal), 32x32 MFMA + split-K x2 ----------------
// 512-thread blocks: 8 waves = 4 q-waves (32 q-rows each, 128 q/group) x 2 K-halves.
// Each iteration stages TWO 64-row K tiles (even->half0, odd->half1, dbuf'd);
// every wave computes every iteration (no parity idling). Per-block work made
// UNIFORM by pairing q-groups {a, 15-a}: iters = (a+1)+(16-a) = 17 for all blocks
// -> sustained occupancy, no causal-drain. After each pass the two K-halves merge
// their (m,l,O) in LDS (O reuses the K buffer; identical fragment layouts make the
// merge element-wise). kh=0 waves store Y.
__global__ __launch_bounds__(512, 4) void attn_fwd8(const unsigned short* __restrict__ Q,
                                                    const unsigned short* __restrict__ Kg,
                                                    const unsigned short* __restrict__ Vt,
                                                    unsigned short* __restrict__ Y) {
    __shared__ __align__(16) unsigned short Ks[2][2][64 * 64];   // [half][buf], 32 KB
    __shared__ float MLbuf[4][2][32];                            // [qw][m/l][q] 1 KB
    float* __restrict__ om = (float*)&Ks[0][0][0];               // merge O, aliases Ks

    const int bid = blockIdx.x;            // 0..511
    const int xcd = bid & 7;
    const int s   = bid >> 3;              // 0..63
    const int a   = s & 7;                 // pair id 0..7
    const int bh  = (s >> 3) * 8 + xcd;    // 0..63, pinned to this XCD
    const int h   = bh & 15;
    const int b   = bh >> 4;

    const int tid  = threadIdx.x;
    const int w    = tid >> 6;             // 0..7
    const int qw   = w & 3;                // q-wave
    const int kh   = w >> 2;               // K-half
    const int lane = tid & 63;
    const int ql = lane & 31, hi = lane >> 5;

    const size_t rowbase = ((size_t)b * T_SEQ) * C_EMB + (size_t)h * 64;   // Q,K,Y
    const size_t vtbase  = ((size_t)b * 1024 + (size_t)h * 64) * T_SEQ;    // Vt [d][t]

    const int srow = lane >> 3;
    const int scol = ((lane & 7) ^ srow) * 8;

    #pragma unroll 1
    for (int pair = 0; pair < 2; ++pair) {
        const int grp   = pair ? (15 - a) : a;
        const int iters = pair ? (16 - a) : (a + 1);   // nt = 2*iters (always even)
        const int q0  = grp * 128;
        const int qw0 = q0 + qw * 32;

        // Q B-frags for this pass
        short8 qf[4];
        #pragma unroll
        for (int ds = 0; ds < 4; ++ds)
            qf[ds] = *(const short8*)&Q[rowbase + (size_t)(qw0 + ql) * C_EMB + ds * 16 + hi * 8];

        f32x16 o0 = {}, o1 = {};
        float mrun = -1e30f, lsum = 0.0f;

        __syncthreads();   // Ks free (previous pass's merge reads done)
        // stage iteration 0 (tiles 0 and 1) -> buf 0
        {
            #pragma unroll
            for (int i2 = 0; i2 < 2; ++i2) {
                int cb = w * 2 + i2;               // 0..15
                int khs = cb >> 3, cb8 = cb & 7;
                async_load16(&Kg[rowbase + (size_t)(khs * 64 + cb8 * 8 + srow) * C_EMB + scol],
                             (char*)&Ks[khs][0][0] + cb8 * 1024);
            }
        }

        #pragma unroll 1
        for (int i = 0; i < iters; ++i) {
            const int cur = i & 1, nxt = cur ^ 1;
            __syncthreads();   // staged tiles ready; buf[nxt] free

            const int t   = 2 * i + kh;            // this wave's tile
            const int kv0 = t * 64;
            const bool active = (kv0 <= qw0 + 31);

            // V prefetch to regs
            short8 vf0[4], vf1[4];
            if (active) {
                #pragma unroll
                for (int ks = 0; ks < 4; ++ks) {
                    vf0[ks] = *(const short8*)&Vt[vtbase + (size_t)ql * T_SEQ + kv0 + ks * 16 + hi * 8];
                    vf1[ks] = *(const short8*)&Vt[vtbase + (size_t)(32 + ql) * T_SEQ + kv0 + ks * 16 + hi * 8];
                }
            }
            // stage next iteration's tiles
            if (i + 1 < iters) {
                #pragma unroll
                for (int i2 = 0; i2 < 2; ++i2) {
                    int cb = w * 2 + i2;
                    int khs = cb >> 3, cb8 = cb & 7;
                    async_load16(&Kg[rowbase + (size_t)((2 * i + 2 + khs) * 64 + cb8 * 8 + srow) * C_EMB + scol],
                                 (char*)&Ks[khs][nxt][0] + cb8 * 1024);
                }
            }
            if (!active) continue;

            // ---- S^T = K * Q^T ----
            f32x16 sa0 = {}, sa1 = {};
            __builtin_amdgcn_s_setprio(1);
            #pragma unroll
            for (int ds = 0; ds < 4; ++ds) {
                short8 a0 = *(const short8*)((const char*)&Ks[kh][cur][0] + ql * 128 +
                                             ((ds * 32 + hi * 16) ^ ((ql & 7) << 4)));
                short8 a1 = *(const short8*)((const char*)&Ks[kh][cur][0] + (32 + ql) * 128 +
                                             ((ds * 32 + hi * 16) ^ ((ql & 7) << 4)));
                sa0 = __builtin_amdgcn_mfma_f32_32x32x16_bf16(a0, qf[ds], sa0, 0, 0, 0);
                sa1 = __builtin_amdgcn_mfma_f32_32x32x16_bf16(a1, qf[ds], sa1, 0, 0, 0);
            }
            __builtin_amdgcn_s_setprio(0);

            // ---- causal mask ----
            if (kv0 + 63 > qw0) {
                const int qi = qw0 + ql;
                #pragma unroll
                for (int r = 0; r < 16; ++r) {
                    int kl = (r & 3) + 8 * (r >> 2) + 4 * hi;
                    if (kv0 + kl > qi)      sa0[r] = -1e30f;
                    if (kv0 + 32 + kl > qi) sa1[r] = -1e30f;
                }
            }

            // ---- lane-local online softmax, exp2 domain ----
            float mx[8];
            #pragma unroll
            for (int r = 0; r < 8; ++r)
                mx[r] = fmaxf(fmaxf(sa0[r], sa0[r + 8]), fmaxf(sa1[r], sa1[r + 8]));
            mx[0] = fmaxf(mx[0], mx[4]); mx[1] = fmaxf(mx[1], mx[5]);
            mx[2] = fmaxf(mx[2], mx[6]); mx[3] = fmaxf(mx[3], mx[7]);
            float tmax = fmaxf(fmaxf(mx[0], mx[1]), fmaxf(mx[2], mx[3]));
            tmax = fmaxf(tmax, __shfl_xor(tmax, 32));
            if (!__all(tmax <= mrun + 8.0f)) {
                float mn  = fmaxf(mrun, tmax);
                float scl = exp2f(mrun - mn);
                mrun = mn;
                lsum *= scl;
                #pragma unroll
                for (int g = 0; g < 4; ++g)
                    #pragma unroll
                    for (int r2 = 0; r2 < 4; ++r2) {
                        float sc = __shfl(scl, g * 8 + 4 * hi + r2);
                        o0[g * 4 + r2] *= sc;
                        o1[g * 4 + r2] *= sc;
                    }
            }
            #pragma unroll
            for (int r = 0; r < 16; ++r) {
                sa0[r] = exp2f(sa0[r] - mrun);
                sa1[r] = exp2f(sa1[r] - mrun);
            }
            float sm[8];
            #pragma unroll
            for (int r = 0; r < 8; ++r)
                sm[r] = (sa0[r] + sa0[r + 8]) + (sa1[r] + sa1[r + 8]);
            lsum += ((sm[0] + sm[1]) + (sm[2] + sm[3])) + ((sm[4] + sm[5]) + (sm[6] + sm[7]));

            // ---- P -> bf16 packed words ----
            unsigned pw0[8], pw1[8];
            #pragma unroll
            for (int g = 0; g < 4; ++g)
                #pragma unroll
                for (int hh = 0; hh < 2; ++hh) {
                    asm("v_cvt_pk_bf16_f32 %0, %1, %2"
                        : "=v"(pw0[g * 2 + hh]) : "v"(sa0[4 * g + 2 * hh]), "v"(sa0[4 * g + 2 * hh + 1]));
                    asm("v_cvt_pk_bf16_f32 %0, %1, %2"
                        : "=v"(pw1[g * 2 + hh]) : "v"(sa1[4 * g + 2 * hh]), "v"(sa1[4 * g + 2 * hh + 1]));
                }

            // ---- in-register P redistribution ----
            short8 pf[4];
            #pragma unroll
            for (int ks = 0; ks < 4; ++ks) {
                const int g0 = (2 * ks) & 3, g1 = (2 * ks + 1) & 3;
                unsigned a_g0h0, a_g0h1, a_g1h0, a_g1h1;
                if (ks < 2) { a_g0h0 = pw0[g0*2];   a_g0h1 = pw0[g0*2+1];
                              a_g1h0 = pw0[g1*2];   a_g1h1 = pw0[g1*2+1]; }
                else        { a_g0h0 = pw1[g0*2];   a_g0h1 = pw1[g0*2+1];
                              a_g1h0 = pw1[g1*2];   a_g1h1 = pw1[g1*2+1]; }
                unsigned s0 = hi ? a_g0h0 : a_g1h0;
                unsigned s1 = hi ? a_g0h1 : a_g1h1;
                unsigned x0 = (unsigned)__shfl_xor((int)s0, 32);
                unsigned x1 = (unsigned)__shfl_xor((int)s1, 32);
                union { unsigned u[4]; short8 v; } uu;
                uu.u[0] = hi ? x0 : a_g0h0;
                uu.u[1] = hi ? x1 : a_g0h1;
                uu.u[2] = hi ? a_g1h0 : x0;
                uu.u[3] = hi ? a_g1h1 : x1;
                pf[ks] = uu.v;
            }

            // ---- PV ----
            __builtin_amdgcn_s_setprio(1);
            #pragma unroll
            for (int ks = 0; ks < 4; ++ks) {
                o0 = __builtin_amdgcn_mfma_f32_32x32x16_bf16(pf[ks], vf0[ks], o0, 0, 0, 0);
                o1 = __builtin_amdgcn_mfma_f32_32x32x16_bf16(pf[ks], vf1[ks], o1, 0, 0, 0);
            }
            __builtin_amdgcn_s_setprio(0);
        }

        // ---- split-K merge (Ks reused as O buffer) ----
        __syncthreads();   // all K reads done
        float lw = lsum + __shfl_xor(lsum, 32);
        if (kh == 1) {
            #pragma unroll
            for (int r = 0; r < 16; ++r) {
                om[qw * 2048 + r * 64 + lane]        = o0[r];
                om[qw * 2048 + (16 + r) * 64 + lane] = o1[r];
            }
            if (hi == 0) {
                MLbuf[qw][0][ql] = mrun;
                MLbuf[qw][1][ql] = lw;
            }
        }
        __syncthreads();
        if (kh == 0) {
            float m1 = MLbuf[qw][0][ql];
            float l1 = MLbuf[qw][1][ql];
            float mst = fmaxf(mrun, m1);
            float f0 = exp2f(mrun - mst), f1 = exp2f(m1 - mst);
            float linv = 1.0f / (f0 * lw + f1 * l1);
            #pragma unroll
            for (int g = 0; g < 4; ++g)
                #pragma unroll
                for (int r2 = 0; r2 < 4; ++r2) {
                    int row = g * 8 + 4 * hi + r2;
                    float fq0 = __shfl(f0, row);
                    float fq1 = __shfl(f1, row);
                    float li  = __shfl(linv, row);
                    int reg = g * 4 + r2;
                    float v0 = fq0 * o0[reg] + fq1 * om[qw * 2048 + reg * 64 + lane];
                    float v1 = fq0 * o1[reg] + fq1 * om[qw * 2048 + (16 + reg) * 64 + lane];
                    size_t ybase = rowbase + (size_t)(qw0 + row) * C_EMB;
                    Y[ybase + ql]      = f2bf(v0 * li);
                    Y[ybase + 32 + ql] = f2bf(v1 * li);
                }
        }
    }
}

// ---------------- launcher ----------------
extern "C" void kernel_launch(void* const* d_in, const int* in_sizes, int n_in,
                              void* d_out, int out_size, void* d_ws, size_t ws_size,
                              hipStream_t stream) {
    const float* x  = (const float*)d_in[0];
    const float* Wk = (const float*)d_in[1];
    const float* bk = (const float*)d_in[2];
    const float* Wq = (const float*)d_in[3];
    const float* bq = (const float*)d_in[4];
    const float* Wv = (const float*)d_in[5];
    const float* bv = (const float*)d_in[6];
    const float* Wp = (const float*)d_in[7];
    const float* bp = (const float*)d_in[8];

    const size_t SX = (size_t)8192 * 1024;
    const size_t SW = (size_t)1024 * 1024;

    char* ws = (char*)d_ws;
    unsigned short* xb   = (unsigned short*)ws; ws += SX * 2;
    unsigned short* Wqkv = (unsigned short*)ws; ws += 3 * SW * 2;  // [Wq;Wk;Wv] rows
    unsigned short* Wpb  = (unsigned short*)ws; ws += SW * 2;
    unsigned short* qb   = (unsigned short*)ws; ws += SX * 2;
    unsigned short* kb   = (unsigned short*)ws; ws += SX * 2;
    unsigned short* vtb  = (unsigned short*)ws; ws += SX * 2;  // V^T per head [b][h][d][t]
    unsigned short* yb   = (unsigned short*)ws; ws += SX * 2;

    cvt_bf16<<<(int)(SX / 4 / 256), 256, 0, stream>>>(x,  xb, (int)(SX / 4));
    cvt_bf16<<<(int)(SW / 4 / 256), 256, 0, stream>>>(Wq, Wqkv,          (int)(SW / 4));
    cvt_bf16<<<(int)(SW / 4 / 256), 256, 0, stream>>>(Wk, Wqkv + SW,     (int)(SW / 4));
    cvt_bf16<<<(int)(SW / 4 / 256), 256, 0, stream>>>(Wv, Wqkv + 2 * SW, (int)(SW / 4));
    cvt_bf16<<<(int)(SW / 4 / 256), 256, 0, stream>>>(Wp, Wpb,           (int)(SW / 4));

    gemm_qkv<<<dim3(24, 64), 256, 0, stream>>>(xb, Wqkv, bq, bk, bv, qb, kb, vtb);

    attn_fwd8<<<dim3(512), 512, 0, stream>>>(qb, kb, vtb, yb);

    gemm_proj<<<dim3(8, 64), 256, 0, stream>>>(yb, Wpb, bp, (float*)d_out, 8192, 1024, 1024);
}